// Round 1
// baseline (560.709 us; speedup 1.0000x reference)
//
#include <hip/hip_runtime.h>
#include <hip/hip_bf16.h>

// MSSA: x(8,2048,512) -> qkv = x@Wqkv ; scores = (q*s)@(k*s)^T over FULL 512 dims ;
// attn = softmax ; out = attn@v ; result = (out + x)@Wout + bout
// Workspace layout (needs 64MB):
//   qkvb : bf16 [16384][1536]  (q cols 0-511 scaled by 0.125, k cols 512-1023 scaled, v cols 1024-1535)
//   res  : bf16 [16384][512]   (attn_out + x)

typedef __attribute__((ext_vector_type(8))) short bf16x8;
typedef __attribute__((ext_vector_type(4))) float f32x4;

__device__ __forceinline__ unsigned short f2bf(float f) {
  unsigned u = __builtin_bit_cast(unsigned, f);
  u += 0x7fffu + ((u >> 16) & 1u);   // RNE
  return (unsigned short)(u >> 16);
}

// ---------------- GEMM1: qkv = bf16(x) @ bf16(Wqkv), scale q,k cols by 0.125 ----------------
__global__ __launch_bounds__(256) void gemm_qkv(const float* __restrict__ X,
                                                const float* __restrict__ W,
                                                unsigned short* __restrict__ QKV) {
  __shared__ __align__(16) unsigned short Asm[64][40];  // [row][k] pad->2-way conflicts (free)
  __shared__ __align__(16) unsigned short Bsm[64][40];  // [col][k] (B transposed)
  const int tid = threadIdx.x;
  const int wave = tid >> 6, lane = tid & 63;
  const int lg = lane >> 4, ll = lane & 15;
  const int kk = lg * 8;
  const int m0 = blockIdx.y * 64, n0 = blockIdx.x * 64;

  f32x4 acc[4];
#pragma unroll
  for (int i = 0; i < 4; ++i) acc[i] = (f32x4){0.f, 0.f, 0.f, 0.f};

  const int arow = wave * 16 + ll;

  for (int kt = 0; kt < 512; kt += 32) {
    {  // stage A 64x32 fp32->bf16
      const int row = tid >> 2, k0 = (tid & 3) * 8;
      const float* src = X + (size_t)(m0 + row) * 512 + kt + k0;
      bf16x8 v;
#pragma unroll
      for (int i = 0; i < 8; ++i) v[i] = (short)f2bf(src[i]);
      *(bf16x8*)&Asm[row][k0] = v;
    }
    {  // stage B transposed: Bsm[c][k] = W[kt+k][n0+c]
      const int k = tid >> 3, c0 = (tid & 7) * 8;
      const float* src = W + (size_t)(kt + k) * 1536 + n0 + c0;
#pragma unroll
      for (int i = 0; i < 8; ++i) Bsm[c0 + i][k] = f2bf(src[i]);
    }
    __syncthreads();
    bf16x8 a = *(const bf16x8*)&Asm[arow][kk];
#pragma unroll
    for (int nf = 0; nf < 4; ++nf) {
      bf16x8 b = *(const bf16x8*)&Bsm[nf * 16 + ll][kk];
      acc[nf] = __builtin_amdgcn_mfma_f32_16x16x32_bf16(a, b, acc[nf], 0, 0, 0);
    }
    __syncthreads();
  }
  // C/D layout: col = lane&15, row = (lane>>4)*4 + r   [m89]
#pragma unroll
  for (int nf = 0; nf < 4; ++nf) {
    const int col = n0 + nf * 16 + ll;
    const float scl = (col < 1024) ? 0.125f : 1.0f;  // fold SCALE into q and k
#pragma unroll
    for (int r = 0; r < 4; ++r) {
      const int row = m0 + wave * 16 + lg * 4 + r;
      QKV[(size_t)row * 1536 + col] = f2bf(acc[nf][r] * scl);
    }
  }
}

// ---------------- Flash attention + residual: res = bf16(softmax(q k^T) v + x) ----------------
__global__ __launch_bounds__(256) void flash_attn(const unsigned short* __restrict__ QKV,
                                                  const float* __restrict__ X,
                                                  unsigned short* __restrict__ RES) {
  __shared__ __align__(16) unsigned short Ksm[32][520];    // [m][d], pad 8
  __shared__ __align__(16) unsigned short Vt[512][40];     // [d][m], pad 8
  __shared__ __align__(16) unsigned short Psm[4][16][40];  // per-wave P tile
  const int tid = threadIdx.x;
  const int wave = tid >> 6, lane = tid & 63;
  const int lg = lane >> 4, ll = lane & 15;
  const int kk = lg * 8;
  const int b = blockIdx.y, qt = blockIdx.x;
  const size_t qrow_base = (size_t)b * 2048 + qt * 64 + wave * 16;

  // Q fragments held in registers for all 16 k-blocks (A layout: row=lane&15, k=(lane>>4)*8+j)
  bf16x8 qf[16];
  {
    const size_t row = qrow_base + ll;
#pragma unroll
    for (int kb = 0; kb < 16; ++kb)
      qf[kb] = *(const bf16x8*)&QKV[row * 1536 + kb * 32 + kk];
  }

  f32x4 o[32];
#pragma unroll
  for (int i = 0; i < 32; ++i) o[i] = (f32x4){0.f, 0.f, 0.f, 0.f};
  float mrow[4] = {-1e30f, -1e30f, -1e30f, -1e30f};
  float lrow[4] = {0.f, 0.f, 0.f, 0.f};

  for (int mt = 0; mt < 64; ++mt) {
    const int m0 = mt * 32;
    {  // stage K tile [32][512] direct layout
      const int mr = tid >> 3, d0 = (tid & 7) * 64;
      const unsigned short* src = QKV + ((size_t)b * 2048 + m0 + mr) * 1536 + 512 + d0;
#pragma unroll
      for (int i = 0; i < 8; ++i)
        *(bf16x8*)&Ksm[mr][d0 + i * 8] = *(const bf16x8*)&src[i * 8];
    }
    {  // stage V transposed: Vt[d][m]
      const int mr = tid >> 3, d0 = (tid & 7) * 64;
      const unsigned short* src = QKV + ((size_t)b * 2048 + m0 + mr) * 1536 + 1024 + d0;
#pragma unroll
      for (int i = 0; i < 8; ++i) {
        bf16x8 v = *(const bf16x8*)&src[i * 8];
#pragma unroll
        for (int j = 0; j < 8; ++j) Vt[d0 + i * 8 + j][mr] = (unsigned short)v[j];
      }
    }
    __syncthreads();

    // S = Q K^T : 16x32 per wave (2 fragments)
    f32x4 s0 = (f32x4){0.f, 0.f, 0.f, 0.f}, s1 = (f32x4){0.f, 0.f, 0.f, 0.f};
#pragma unroll
    for (int kb = 0; kb < 16; ++kb) {
      bf16x8 b0 = *(const bf16x8*)&Ksm[ll][kb * 32 + kk];
      bf16x8 b1 = *(const bf16x8*)&Ksm[16 + ll][kb * 32 + kk];
      s0 = __builtin_amdgcn_mfma_f32_16x16x32_bf16(qf[kb], b0, s0, 0, 0, 0);
      s1 = __builtin_amdgcn_mfma_f32_16x16x32_bf16(qf[kb], b1, s1, 0, 0, 0);
    }

    // online softmax: row r lives in the 16-lane group, row index lg*4+r
    float alpha[4];
#pragma unroll
    for (int r = 0; r < 4; ++r) {
      float mx = fmaxf(s0[r], s1[r]);
      mx = fmaxf(mx, __shfl_xor(mx, 1));
      mx = fmaxf(mx, __shfl_xor(mx, 2));
      mx = fmaxf(mx, __shfl_xor(mx, 4));
      mx = fmaxf(mx, __shfl_xor(mx, 8));
      const float mn = fmaxf(mrow[r], mx);
      alpha[r] = __expf(mrow[r] - mn);
      mrow[r] = mn;
      const float p0 = __expf(s0[r] - mn);
      const float p1 = __expf(s1[r] - mn);
      s0[r] = p0;
      s1[r] = p1;
      float rs = p0 + p1;
      rs += __shfl_xor(rs, 1);
      rs += __shfl_xor(rs, 2);
      rs += __shfl_xor(rs, 4);
      rs += __shfl_xor(rs, 8);
      lrow[r] = lrow[r] * alpha[r] + rs;
    }

    // P -> LDS (bf16) to redistribute into A-fragment layout
#pragma unroll
    for (int r = 0; r < 4; ++r) {
      Psm[wave][lg * 4 + r][ll] = f2bf(s0[r]);
      Psm[wave][lg * 4 + r][16 + ll] = f2bf(s1[r]);
    }

    // rescale O only when some row max moved (most tiles skip: alpha==1)
    const bool need = (alpha[0] < 1.f) || (alpha[1] < 1.f) || (alpha[2] < 1.f) || (alpha[3] < 1.f);
    if (__any(need)) {
#pragma unroll
      for (int f = 0; f < 32; ++f) {
        o[f][0] *= alpha[0];
        o[f][1] *= alpha[1];
        o[f][2] *= alpha[2];
        o[f][3] *= alpha[3];
      }
    }

    // PV: O(16x512) += P(16x32) @ V(32x512)
    bf16x8 pa = *(const bf16x8*)&Psm[wave][ll][kk];
#pragma unroll
    for (int vf = 0; vf < 32; ++vf) {
      bf16x8 vb = *(const bf16x8*)&Vt[vf * 16 + ll][kk];
      o[vf] = __builtin_amdgcn_mfma_f32_16x16x32_bf16(pa, vb, o[vf], 0, 0, 0);
    }
    __syncthreads();
  }

  // epilogue: normalize, add residual x, store bf16
  float rl[4];
#pragma unroll
  for (int r = 0; r < 4; ++r) rl[r] = 1.0f / lrow[r];
#pragma unroll
  for (int vf = 0; vf < 32; ++vf) {
    const int col = vf * 16 + ll;
#pragma unroll
    for (int r = 0; r < 4; ++r) {
      const size_t row = qrow_base + lg * 4 + r;
      const float val = o[vf][r] * rl[r] + X[row * 512 + col];
      RES[row * 512 + col] = f2bf(val);
    }
  }
}

// ---------------- GEMM2: out = res @ bf16(Wout) + bout (fp32 out) ----------------
__global__ __launch_bounds__(256) void gemm_out(const unsigned short* __restrict__ A,
                                                const float* __restrict__ W,
                                                const float* __restrict__ bias,
                                                float* __restrict__ OUT) {
  __shared__ __align__(16) unsigned short Asm[64][40];
  __shared__ __align__(16) unsigned short Bsm[64][40];
  const int tid = threadIdx.x;
  const int wave = tid >> 6, lane = tid & 63;
  const int lg = lane >> 4, ll = lane & 15;
  const int kk = lg * 8;
  const int m0 = blockIdx.y * 64, n0 = blockIdx.x * 64;

  f32x4 acc[4];
#pragma unroll
  for (int i = 0; i < 4; ++i) acc[i] = (f32x4){0.f, 0.f, 0.f, 0.f};

  const int arow = wave * 16 + ll;

  for (int kt = 0; kt < 512; kt += 32) {
    {  // stage A (already bf16)
      const int row = tid >> 2, k0 = (tid & 3) * 8;
      *(bf16x8*)&Asm[row][k0] = *(const bf16x8*)&A[(size_t)(m0 + row) * 512 + kt + k0];
    }
    {  // stage B transposed fp32->bf16
      const int k = tid >> 3, c0 = (tid & 7) * 8;
      const float* src = W + (size_t)(kt + k) * 512 + n0 + c0;
#pragma unroll
      for (int i = 0; i < 8; ++i) Bsm[c0 + i][k] = f2bf(src[i]);
    }
    __syncthreads();
    bf16x8 a = *(const bf16x8*)&Asm[arow][kk];
#pragma unroll
    for (int nf = 0; nf < 4; ++nf) {
      bf16x8 b = *(const bf16x8*)&Bsm[nf * 16 + ll][kk];
      acc[nf] = __builtin_amdgcn_mfma_f32_16x16x32_bf16(a, b, acc[nf], 0, 0, 0);
    }
    __syncthreads();
  }
#pragma unroll
  for (int nf = 0; nf < 4; ++nf) {
    const int col = n0 + nf * 16 + ll;
    const float bv = bias[col];
#pragma unroll
    for (int r = 0; r < 4; ++r) {
      const int row = m0 + wave * 16 + lg * 4 + r;
      OUT[(size_t)row * 512 + col] = acc[nf][r] + bv;
    }
  }
}

extern "C" void kernel_launch(void* const* d_in, const int* in_sizes, int n_in,
                              void* d_out, int out_size, void* d_ws, size_t ws_size,
                              hipStream_t stream) {
  const float* x = (const float*)d_in[0];     // [8,2048,512]
  const float* Wqkv = (const float*)d_in[1];  // [512,1536]
  const float* Wout = (const float*)d_in[2];  // [512,512]
  const float* bout = (const float*)d_in[3];  // [512]
  float* out = (float*)d_out;                 // [8,2048,512] fp32

  unsigned short* qkvb = (unsigned short*)d_ws;          // 16384*1536 bf16 = 50.3MB
  unsigned short* res = qkvb + (size_t)16384 * 1536;     // 16384*512  bf16 = 16.8MB

  gemm_qkv<<<dim3(24, 256), 256, 0, stream>>>(x, Wqkv, qkvb);
  flash_attn<<<dim3(32, 8), 256, 0, stream>>>(qkvb, x, res);
  gemm_out<<<dim3(8, 256), 256, 0, stream>>>(res, Wout, bout, out);
}

// Round 2
// 376.102 us; speedup vs baseline: 1.4908x; 1.4908x over previous
//
#include <hip/hip_runtime.h>
#include <hip/hip_bf16.h>

// MSSA: x(8,2048,512) -> qkv = x@Wqkv ; scores = (q*s)@(k*s)^T over FULL 512 dims ;
// attn = softmax ; out = attn@v ; result = (out + x)@Wout + bout
// Workspace (67.1MB, same as R1):
//   qkvb : bf16 [16384][1536]  q cols 0-511 (scaled 0.125), k cols 512-1023 (scaled),
//                              v cols 1024-1535 -- v cols are DEAD after transpose_v,
//                              flash_attn reuses them to store res = bf16(attn_out + x)
//   VT   : bf16 [512][16384]   V transposed (d-major)

typedef __attribute__((ext_vector_type(8))) short bf16x8;
typedef __attribute__((ext_vector_type(4))) float f32x4;

__device__ __forceinline__ unsigned short f2bf(float f) {
  unsigned u = __builtin_bit_cast(unsigned, f);
  u += 0x7fffu + ((u >> 16) & 1u);   // RNE
  return (unsigned short)(u >> 16);
}

// ---------------- GEMM1: qkv = bf16(x) @ bf16(Wqkv), scale q,k cols by 0.125 ----------------
__global__ __launch_bounds__(256) void gemm_qkv(const float* __restrict__ X,
                                                const float* __restrict__ W,
                                                unsigned short* __restrict__ QKV) {
  __shared__ __align__(16) unsigned short Asm[64][40];
  __shared__ __align__(16) unsigned short Bsm[64][40];
  const int tid = threadIdx.x;
  const int wave = tid >> 6, lane = tid & 63;
  const int lg = lane >> 4, ll = lane & 15;
  const int kk = lg * 8;
  const int m0 = blockIdx.y * 64, n0 = blockIdx.x * 64;

  f32x4 acc[4];
#pragma unroll
  for (int i = 0; i < 4; ++i) acc[i] = (f32x4){0.f, 0.f, 0.f, 0.f};

  const int arow = wave * 16 + ll;

  for (int kt = 0; kt < 512; kt += 32) {
    {  // stage A 64x32 fp32->bf16 (b128 writes, ~2-way)
      const int row = tid >> 2, k0 = (tid & 3) * 8;
      const float* src = X + (size_t)(m0 + row) * 512 + kt + k0;
      bf16x8 v;
#pragma unroll
      for (int i = 0; i < 8; ++i) v[i] = (short)f2bf(src[i]);
      *(bf16x8*)&Asm[row][k0] = v;
    }
    {  // stage B transposed: Bsm[c][k] = W[kt+k][n0+c]; c=(tid&7)+8i -> uniform banks
      const int k = tid >> 3, cl = tid & 7;
      const float* src = W + (size_t)(kt + k) * 1536 + n0 + cl;
#pragma unroll
      for (int i = 0; i < 8; ++i) Bsm[cl + i * 8][k] = f2bf(src[i * 8]);
    }
    __syncthreads();
    bf16x8 a = *(const bf16x8*)&Asm[arow][kk];
#pragma unroll
    for (int nf = 0; nf < 4; ++nf) {
      bf16x8 b = *(const bf16x8*)&Bsm[nf * 16 + ll][kk];
      acc[nf] = __builtin_amdgcn_mfma_f32_16x16x32_bf16(a, b, acc[nf], 0, 0, 0);
    }
    __syncthreads();
  }
#pragma unroll
  for (int nf = 0; nf < 4; ++nf) {
    const int col = n0 + nf * 16 + ll;
    const float scl = (col < 1024) ? 0.125f : 1.0f;
#pragma unroll
    for (int r = 0; r < 4; ++r) {
      const int row = m0 + wave * 16 + lg * 4 + r;
      QKV[(size_t)row * 1536 + col] = f2bf(acc[nf][r] * scl);
    }
  }
}

// ---------------- Transpose V: VT[d][m] = qkv[m][1024+d], register 8x8 transpose ----------------
__global__ __launch_bounds__(256) void transpose_v(const unsigned short* __restrict__ QKV,
                                                   unsigned short* __restrict__ VT) {
  const int t = threadIdx.x;
  const int m0 = blockIdx.x * 128 + (t & 15) * 8;
  const int d0 = blockIdx.y * 128 + (t >> 4) * 8;
  bf16x8 r[8];
#pragma unroll
  for (int j = 0; j < 8; ++j)
    r[j] = *(const bf16x8*)&QKV[(size_t)(m0 + j) * 1536 + 1024 + d0];
#pragma unroll
  for (int i = 0; i < 8; ++i) {
    bf16x8 o;
#pragma unroll
    for (int j = 0; j < 8; ++j) o[j] = r[j][i];
    *(bf16x8*)&VT[(size_t)(d0 + i) * 16384 + m0] = o;
  }
}

// ---------------- Flash attention + residual: qkv v-cols <- bf16(softmax(q k^T) v + x) ----------------
__global__ __launch_bounds__(256) void flash_attn(const unsigned short* __restrict__ QKV,
                                                  const unsigned short* __restrict__ VT,
                                                  const float* __restrict__ X,
                                                  unsigned short* __restrict__ RES) {
  __shared__ __align__(16) unsigned short Ksm[32][520];    // [kv][d], pad 8 -> reads/writes uniform
  __shared__ __align__(16) unsigned short Vsm[512][40];    // [d][kv], pad 8 -> reads/writes uniform
  __shared__ __align__(16) unsigned short Psm[4][16][40];  // per-wave P tile
  const int tid = threadIdx.x;
  const int wave = tid >> 6, lane = tid & 63;
  const int lg = lane >> 4, ll = lane & 15;
  const int kk = lg * 8;
  const int b = blockIdx.x, qt = blockIdx.y;  // grid(8,32): linear%8 = b -> one batch per XCD
  const size_t qrow_base = (size_t)b * 2048 + qt * 64 + wave * 16;

  // Q fragments in registers (A layout: row=lane&15, k=(lane>>4)*8+j)
  bf16x8 qf[16];
  {
    const size_t row = qrow_base + ll;
#pragma unroll
    for (int kb = 0; kb < 16; ++kb)
      qf[kb] = *(const bf16x8*)&QKV[row * 1536 + kb * 32 + kk];
  }

  // T14 prefetch registers: K rows (p*4 + tid>>6), V rows (p*64 + tid>>2)
  const int krow = tid >> 6, kin = (tid & 63) * 8;         // K: row-in-group, inner ushort
  const int vrow = tid >> 2, vin = (tid & 3) * 8;          // V: d-in-group, inner ushort
  const unsigned short* Kg = QKV + ((size_t)b * 2048) * 1536 + 512;
  const unsigned short* Vg = VT + (size_t)b * 2048;

  bf16x8 kr[8], vr[8];
#pragma unroll
  for (int p = 0; p < 8; ++p) {
    kr[p] = *(const bf16x8*)&Kg[(size_t)(p * 4 + krow) * 1536 + kin];
    vr[p] = *(const bf16x8*)&Vg[(size_t)(p * 64 + vrow) * 16384 + vin];
  }

  f32x4 o[32];
#pragma unroll
  for (int i = 0; i < 32; ++i) o[i] = (f32x4){0.f, 0.f, 0.f, 0.f};
  float mrow[4] = {-1e30f, -1e30f, -1e30f, -1e30f};
  float lrow[4] = {0.f, 0.f, 0.f, 0.f};

  for (int mt = 0; mt < 64; ++mt) {
    __syncthreads();  // all waves done reading previous tile
    {                 // commit prefetched tile to LDS (b128 row-writes, uniform banks)
#pragma unroll
      for (int p = 0; p < 8; ++p) {
        *(bf16x8*)&Ksm[p * 4 + krow][kin] = kr[p];
        *(bf16x8*)&Vsm[p * 64 + vrow][vin] = vr[p];
      }
    }
    __syncthreads();
    if (mt < 63) {  // issue next-tile loads now; latency hides under QK+softmax+PV
      const size_t moff = (size_t)(mt + 1) * 32;
#pragma unroll
      for (int p = 0; p < 8; ++p) {
        kr[p] = *(const bf16x8*)&Kg[(moff + p * 4 + krow) * 1536 + kin];
        vr[p] = *(const bf16x8*)&Vg[(size_t)(p * 64 + vrow) * 16384 + moff + vin];
      }
    }

    // S = Q K^T : 16x32 per wave
    f32x4 s0 = (f32x4){0.f, 0.f, 0.f, 0.f}, s1 = (f32x4){0.f, 0.f, 0.f, 0.f};
#pragma unroll
    for (int kb = 0; kb < 16; ++kb) {
      bf16x8 b0 = *(const bf16x8*)&Ksm[ll][kb * 32 + kk];
      bf16x8 b1 = *(const bf16x8*)&Ksm[16 + ll][kb * 32 + kk];
      s0 = __builtin_amdgcn_mfma_f32_16x16x32_bf16(qf[kb], b0, s0, 0, 0, 0);
      s1 = __builtin_amdgcn_mfma_f32_16x16x32_bf16(qf[kb], b1, s1, 0, 0, 0);
    }

    // online softmax (rows lg*4+r, reduce over 16-lane group)
    float alpha[4];
#pragma unroll
    for (int r = 0; r < 4; ++r) {
      float mx = fmaxf(s0[r], s1[r]);
      mx = fmaxf(mx, __shfl_xor(mx, 1));
      mx = fmaxf(mx, __shfl_xor(mx, 2));
      mx = fmaxf(mx, __shfl_xor(mx, 4));
      mx = fmaxf(mx, __shfl_xor(mx, 8));
      const float mn = fmaxf(mrow[r], mx);
      alpha[r] = __expf(mrow[r] - mn);
      mrow[r] = mn;
      const float p0 = __expf(s0[r] - mn);
      const float p1 = __expf(s1[r] - mn);
      s0[r] = p0;
      s1[r] = p1;
      float rs = p0 + p1;
      rs += __shfl_xor(rs, 1);
      rs += __shfl_xor(rs, 2);
      rs += __shfl_xor(rs, 4);
      rs += __shfl_xor(rs, 8);
      lrow[r] = lrow[r] * alpha[r] + rs;
    }

#pragma unroll
    for (int r = 0; r < 4; ++r) {
      Psm[wave][lg * 4 + r][ll] = f2bf(s0[r]);
      Psm[wave][lg * 4 + r][16 + ll] = f2bf(s1[r]);
    }

    const bool need = (alpha[0] < 1.f) || (alpha[1] < 1.f) || (alpha[2] < 1.f) || (alpha[3] < 1.f);
    if (__any(need)) {
#pragma unroll
      for (int f = 0; f < 32; ++f) {
        o[f][0] *= alpha[0];
        o[f][1] *= alpha[1];
        o[f][2] *= alpha[2];
        o[f][3] *= alpha[3];
      }
    }

    // PV: O(16x512) += P(16x32) @ V(32x512); Vsm is [d][kv] so B-frag is a row read
    bf16x8 pa = *(const bf16x8*)&Psm[wave][ll][kk];
#pragma unroll
    for (int vf = 0; vf < 32; ++vf) {
      bf16x8 vb = *(const bf16x8*)&Vsm[vf * 16 + ll][kk];
      o[vf] = __builtin_amdgcn_mfma_f32_16x16x32_bf16(pa, vb, o[vf], 0, 0, 0);
    }
  }

  // epilogue: normalize, add residual, store bf16 into qkv's dead v-columns (stride 1536)
  float rl[4];
#pragma unroll
  for (int r = 0; r < 4; ++r) rl[r] = 1.0f / lrow[r];
#pragma unroll
  for (int vf = 0; vf < 32; ++vf) {
    const int col = vf * 16 + ll;
#pragma unroll
    for (int r = 0; r < 4; ++r) {
      const size_t row = qrow_base + lg * 4 + r;
      const float val = o[vf][r] * rl[r] + X[row * 512 + col];
      RES[row * 1536 + 1024 + col] = f2bf(val);
    }
  }
}

// ---------------- GEMM2: out = res @ bf16(Wout) + bout (res strided in qkv v-cols) ----------------
__global__ __launch_bounds__(256) void gemm_out(const unsigned short* __restrict__ A,
                                                const float* __restrict__ W,
                                                const float* __restrict__ bias,
                                                float* __restrict__ OUT) {
  __shared__ __align__(16) unsigned short Asm[64][40];
  __shared__ __align__(16) unsigned short Bsm[64][40];
  const int tid = threadIdx.x;
  const int wave = tid >> 6, lane = tid & 63;
  const int lg = lane >> 4, ll = lane & 15;
  const int kk = lg * 8;
  const int m0 = blockIdx.y * 64, n0 = blockIdx.x * 64;

  f32x4 acc[4];
#pragma unroll
  for (int i = 0; i < 4; ++i) acc[i] = (f32x4){0.f, 0.f, 0.f, 0.f};

  const int arow = wave * 16 + ll;

  for (int kt = 0; kt < 512; kt += 32) {
    {  // stage A (bf16, strided 1536, offset 1024)
      const int row = tid >> 2, k0 = (tid & 3) * 8;
      *(bf16x8*)&Asm[row][k0] = *(const bf16x8*)&A[(size_t)(m0 + row) * 1536 + 1024 + kt + k0];
    }
    {  // stage B transposed, uniform-bank writes
      const int k = tid >> 3, cl = tid & 7;
      const float* src = W + (size_t)(kt + k) * 512 + n0 + cl;
#pragma unroll
      for (int i = 0; i < 8; ++i) Bsm[cl + i * 8][k] = f2bf(src[i * 8]);
    }
    __syncthreads();
    bf16x8 a = *(const bf16x8*)&Asm[arow][kk];
#pragma unroll
    for (int nf = 0; nf < 4; ++nf) {
      bf16x8 b = *(const bf16x8*)&Bsm[nf * 16 + ll][kk];
      acc[nf] = __builtin_amdgcn_mfma_f32_16x16x32_bf16(a, b, acc[nf], 0, 0, 0);
    }
    __syncthreads();
  }
#pragma unroll
  for (int nf = 0; nf < 4; ++nf) {
    const int col = n0 + nf * 16 + ll;
    const float bv = bias[col];
#pragma unroll
    for (int r = 0; r < 4; ++r) {
      const int row = m0 + wave * 16 + lg * 4 + r;
      OUT[(size_t)row * 512 + col] = acc[nf][r] + bv;
    }
  }
}

extern "C" void kernel_launch(void* const* d_in, const int* in_sizes, int n_in,
                              void* d_out, int out_size, void* d_ws, size_t ws_size,
                              hipStream_t stream) {
  const float* x = (const float*)d_in[0];     // [8,2048,512]
  const float* Wqkv = (const float*)d_in[1];  // [512,1536]
  const float* Wout = (const float*)d_in[2];  // [512,512]
  const float* bout = (const float*)d_in[3];  // [512]
  float* out = (float*)d_out;                 // [8,2048,512] fp32

  unsigned short* qkvb = (unsigned short*)d_ws;        // 16384*1536 bf16 = 50.3MB
  unsigned short* VT = qkvb + (size_t)16384 * 1536;    // 512*16384  bf16 = 16.8MB

  gemm_qkv<<<dim3(24, 256), 256, 0, stream>>>(x, Wqkv, qkvb);
  transpose_v<<<dim3(128, 4), 256, 0, stream>>>(qkvb, VT);
  flash_attn<<<dim3(8, 32), 256, 0, stream>>>(qkvb, VT, x, qkvb);
  gemm_out<<<dim3(8, 256), 256, 0, stream>>>(qkvb, Wout, bout, out);
}